// Round 12
// baseline (1541.134 us; speedup 1.0000x reference)
//
#include <hip/hip_runtime.h>
#include <math.h>

#define NBLK 64
#define NTHR 576        // 9 waves: 8 compute + 1 fire/job wave
#define LSEQ 1024
#define NCOPY 16        // replicated mailboxes: block b polls copy b>>2

typedef unsigned int u32;
typedef unsigned short u16;
typedef unsigned long long u64;

// ---------------- scalar helpers ----------------
__device__ __forceinline__ float bf2f(u16 u){ union{u32 i;float f;}v; v.i=(u32)u<<16; return v.f; }
__device__ __forceinline__ u16 f2bf(float f){ union{float f;u32 i;}v; v.f=f; u32 x=v.i;
  return (u16)((x + 0x7fffu + ((x>>16)&1u)) >> 16); }
__device__ __forceinline__ float u2f(u32 u){ union{u32 i;float f;}v; v.i=u; return v.f; }
__device__ __forceinline__ u32  f2u(float f){ union{float f;u32 i;}v; v.f=f; return v.i; }
__device__ __forceinline__ float sigm(float x){ return 1.f/(1.f+__expf(-x)); }

// coherent (agent-scope) 8B atoms: (tag<<32)|payload
__device__ __forceinline__ u64 gld64(const u64* p){ return __hip_atomic_load(const_cast<u64*>(p), __ATOMIC_RELAXED, __HIP_MEMORY_SCOPE_AGENT); }
__device__ __forceinline__ void gst64(u64* p, u64 v){ __hip_atomic_store(p, v, __ATOMIC_RELAXED, __HIP_MEMORY_SCOPE_AGENT); }
__device__ __forceinline__ u64 pollt(const u64* p, u32 tag){
  u64 v; int n = 0;
  do { v = gld64(p); } while ((u32)(v>>32) != tag && ++n < (1<<20));
  return v;
}

// ---------------- reductions ----------------
// DPP full-wave(64) sum; result uniform. VALU-only.
__device__ __forceinline__ float wred(float a){
  a += __int_as_float(__builtin_amdgcn_update_dpp(0, __float_as_int(a), 0x111, 0xf, 0xf, true));
  a += __int_as_float(__builtin_amdgcn_update_dpp(0, __float_as_int(a), 0x112, 0xf, 0xf, true));
  a += __int_as_float(__builtin_amdgcn_update_dpp(0, __float_as_int(a), 0x114, 0xf, 0xf, true));
  a += __int_as_float(__builtin_amdgcn_update_dpp(0, __float_as_int(a), 0x118, 0xf, 0xf, true));
  a += __int_as_float(__builtin_amdgcn_update_dpp(0, __float_as_int(a), 0x142, 0xa, 0xf, true));
  a += __int_as_float(__builtin_amdgcn_update_dpp(0, __float_as_int(a), 0x143, 0xc, 0xf, true));
  return __int_as_float(__builtin_amdgcn_readlane(__float_as_int(a), 63));
}
__device__ __forceinline__ float wredsh(float a){
  #pragma unroll
  for (int off = 32; off; off >>= 1) a += __shfl_xor(a, off);
  return a;
}
__device__ __forceinline__ float wredmaxsh(float a){
  #pragma unroll
  for (int off = 32; off; off >>= 1) a = fmaxf(a, __shfl_xor(a, off));
  return a;
}

// ---------------- packed dot helpers ----------------
__device__ __forceinline__ float dot8p(uint4 w, float4 a, float4 b2){
  float s;
  s  = u2f(w.x<<16)*a.x  + u2f(w.x&0xffff0000u)*a.y;
  s += u2f(w.y<<16)*a.z  + u2f(w.y&0xffff0000u)*a.w;
  s += u2f(w.z<<16)*b2.x + u2f(w.z&0xffff0000u)*b2.y;
  s += u2f(w.w<<16)*b2.z + u2f(w.w&0xffff0000u)*b2.w;
  return s;
}
__device__ __forceinline__ float dot4f(float4 w, float4 x){
  return w.x*x.x + w.y*x.y + w.z*x.z + w.w*x.w;
}
__device__ __forceinline__ uint4 pk8(float4 a, float4 b2){
  uint4 r;
  r.x = (u32)f2bf(a.x)  | ((u32)f2bf(a.y)<<16);
  r.y = (u32)f2bf(a.z)  | ((u32)f2bf(a.w)<<16);
  r.z = (u32)f2bf(b2.x) | ((u32)f2bf(b2.y)<<16);
  r.w = (u32)f2bf(b2.z) | ((u32)f2bf(b2.w)<<16);
  return r;
}

#define SMEM_BYTES 150048

// wave-8 deferred log-softmax jobs (round-robin across blocks, off critical path)
#define RUN_JOBS() do { \
  if (wv == 8){ \
    if (dBV && b == dBo1){ \
      u64 v_ = pollt(XS + dBSlot*64 + lane, dBTag); \
      float x0 = sA0 + bf2f((u16)(v_ & 0xffff)); \
      float x1 = sA1 + bf2f((u16)((v_>>16) & 0xffff)); \
      x0 = (lane < dBcur) ? x0 : -__builtin_inff(); \
      x1 = (lane + 64 < dBcur) ? x1 : -__builtin_inff(); \
      float m_ = wredmaxsh(fmaxf(x0, x1)); \
      float s_ = wredsh(__expf(x0 - m_) + __expf(x1 - m_)); \
      float la_ = (dBarg < 64) ? __shfl(x0, dBarg) : __shfl(x1, dBarg - 64); \
      if (lane == 0) nllw += (m_ + logf(s_)) - la_; \
    } \
    if (dAV && (b == dAo1 || b == dAo2)){ \
      const u64* P_ = XP + ((size_t)(dASlot*64 + lane))*64 + ((b == dAo2) ? 32 : 0); \
      float h0_ = 0.f, h1_ = 0.f; \
      for (int c_ = 0; c_ < 2; ++c_){ \
        u64 vv_[16]; int bad_; int nn_ = 0; \
        do { bad_ = 0; \
          _Pragma("unroll") for (int j_ = 0; j_ < 16; ++j_) vv_[j_] = gld64(P_ + c_*16 + j_); \
          _Pragma("unroll") for (int j_ = 0; j_ < 16; ++j_) bad_ |= ((u32)(vv_[j_]>>32) != dATag); \
        } while (bad_ && ++nn_ < (1<<20)); \
        _Pragma("unroll") for (int j_ = 0; j_ < 16; ++j_){ \
          h0_ += bf2f((u16)(vv_[j_] & 0xffff)); h1_ += bf2f((u16)((vv_[j_]>>16) & 0xffff)); } \
      } \
      if (b == dAo2) gst64(XS + dASlot*64 + lane, ((u64)dATag<<32) | (u32)f2bf(h0_) | ((u32)f2bf(h1_)<<16)); \
      else { sA0 = h0_; sA1 = h1_; } \
    } \
    if (aeV && b == aeOwn){ \
      u64 v_ = pollt(XE + aeSlot*64 + lane, aeTag); \
      float p0_ = wredsh(bf2f((u16)(v_ & 0xffff))); \
      float p1_ = wredsh(bf2f((u16)((v_>>16) & 0xffff))); \
      if (lane == 0){ \
        float l0_ = p0_ + be2_0, l1_ = p1_ + be2_1; \
        float m_ = fmaxf(l0_, l1_); \
        nllw += m_ + logf(__expf(l0_-m_) + __expf(l1_-m_)) - (aeSel ? l1_ : l0_); \
      } \
    } \
  } \
} while(0)

#define SHIFT_JOBS() do { \
  dBV = dAV; dBSlot = dASlot; dBo1 = dAo1; dBTag = dATag; dBcur = dAcur; dBarg = dAarg; \
  dAV = 0; aeV = 0; \
} while(0)

// replicated fire: NCOPY private copies, consumers poll copy b>>2
#define FIRE_NG(par_, which_, val_) do { \
  u64 atom_ = ((u64)ph<<32) | f2u(val_); \
  _Pragma("unroll") \
  for (int c_ = 0; c_ < NCOPY; ++c_) \
    gst64(&Xng[((size_t)((par_)*NCOPY + c_)*512 + d)*2 + (which_)], atom_); \
} while(0)

__global__ void __launch_bounds__(NTHR, 1)
dgmg_kernel(const int* __restrict__ actions, const int* __restrict__ argseq,
            const float* __restrict__ node_init, const float* __restrict__ w_nip, const float* __restrict__ b_nip,
            const float* __restrict__ w_e1, const float* __restrict__ b_e1,
            const float* __restrict__ w_e2, const float* __restrict__ b_e2,
            const float* __restrict__ w_q, const float* __restrict__ b_q,
            const float* __restrict__ w_k,
            const float* __restrict__ wih_n, const float* __restrict__ whh_n,
            const float* __restrict__ bih_n, const float* __restrict__ bhh_n,
            const float* __restrict__ wih_g, const float* __restrict__ whh_g,
            const float* __restrict__ bih_g, const float* __restrict__ bhh_g,
            const float* __restrict__ graph0,
            float* __restrict__ out, unsigned char* __restrict__ ws)
{
  extern __shared__ unsigned char smem[];
  u16* s_wihg = (u16*)smem;                 // [24][512] packed bf16
  u16* s_whhg = s_wihg + 24*512;
  u16* s_wihn = s_whhg + 24*512;
  u16* s_whhn = s_wihn + 24*512;
  u16* s_we1  = s_whhn + 24*512;            // [8][1024]
  u16* s_wq   = s_we1 + 8*1024;             // [8][1024]
  float* s_g    = (float*)(s_wq + 8*1024);  // staged graph vector
  float* s_nc   = s_g + 512;                // staged ncur
  float* s_curv = s_nc + 512;               // current node vector pre-update
  float* s_h0   = s_curv + 512;             // fresh-node embedding
  float* s_kloc = s_h0 + 512;               // [8][128] transposed k-cache [dim][node]
  float* s_bihg = s_kloc + 1024;            // [24]
  float* s_bhhg = s_bihg + 24;
  float* s_bihn = s_bhhg + 24;
  float* s_bhhn = s_bihn + 24;
  float* s_be1  = s_bhhn + 24;              // [8]
  float* s_bq   = s_be1 + 8;                // [8]
  float* s_q8   = s_bq + 8;                 // [8]
  float* s_red  = s_q8 + 8;                 // [16]
  u16*   s_gin  = (u16*)(s_red + 16);       // [128][24] gi_n freeze cache (bf16)

  const int b = blockIdx.x, tid = threadIdx.x;
  const int wv = tid >> 6, lane = tid & 63;
  const int d = b*8 + ((wv < 8) ? wv : 0);
  const int cpy = b >> 2;                   // this block's mailbox copy

  // workspace: tagged u64 atoms (Xng/Xh replicated NCOPY ways)
  u64* Xng = (u64*)ws;         // [2][NCOPY][512][2] = 32768 atoms
  u64* Xh  = Xng + 32768;      // [NCOPY][512] = 8192
  u64* XE  = Xh + 8192;        // [4][64]
  u64* XP  = XE + 256;         // [4][64][64]
  u64* XS  = XP + 16384;       // [4][64]
  u64* XN  = XS + 256;         // [64]

  // ---------------- init: biases + packed bf16 weight slices ----------------
  if (tid < 24){
    int ld = tid/3, gt = tid%3;
    int row = gt*512 + b*8 + ld;
    s_bihg[tid] = bih_g[row]; s_bhhg[tid] = bhh_g[row];
    s_bihn[tid] = bih_n[row]; s_bhhn[tid] = bhh_n[row];
  }
  if (tid < 8){ s_be1[tid] = b_e1[b*8+tid]; s_bq[tid] = b_q[b*8+tid]; }

  for (int r = wv; r < 24; r += 9){           // all 9 waves pack
    int ld = r/3, gt = r%3;
    long grow = (long)(gt*512 + b*8 + ld) * 512;
    float4 a0, a1;
    a0 = *(const float4*)&wih_g[grow + lane*8]; a1 = *(const float4*)&wih_g[grow + lane*8 + 4];
    *(uint4*)&s_wihg[r*512 + lane*8] = pk8(a0, a1);
    a0 = *(const float4*)&whh_g[grow + lane*8]; a1 = *(const float4*)&whh_g[grow + lane*8 + 4];
    *(uint4*)&s_whhg[r*512 + lane*8] = pk8(a0, a1);
    a0 = *(const float4*)&wih_n[grow + lane*8]; a1 = *(const float4*)&wih_n[grow + lane*8 + 4];
    *(uint4*)&s_wihn[r*512 + lane*8] = pk8(a0, a1);
    a0 = *(const float4*)&whh_n[grow + lane*8]; a1 = *(const float4*)&whh_n[grow + lane*8 + 4];
    *(uint4*)&s_whhn[r*512 + lane*8] = pk8(a0, a1);
  }
  if (wv < 8){
    long grow = (long)(b*8 + wv) * 1024;
    #pragma unroll
    for (int h = 0; h < 2; ++h){
      float4 a0 = *(const float4*)&w_e1[grow + h*512 + lane*8];
      float4 a1 = *(const float4*)&w_e1[grow + h*512 + lane*8 + 4];
      *(uint4*)&s_we1[wv*1024 + h*512 + lane*8] = pk8(a0, a1);
      float4 q0 = *(const float4*)&w_q[grow + h*512 + lane*8];
      float4 q1 = *(const float4*)&w_q[grow + h*512 + lane*8 + 4];
      *(uint4*)&s_wq[wv*1024 + h*512 + lane*8] = pk8(q0, q1);
    }
  }
  float we2_0 = w_e2[d], we2_1 = w_e2[512+d];
  float be2_0 = b_e2[0], be2_1 = b_e2[1];
  float nllw = 0.f, sA0 = 0.f, sA1 = 0.f;

  // job state
  int aeV=0, aeSlot=0, aeSel=0, aeOwn=0; u32 aeTag=0;
  int dAV=0, dASlot=0, dAo1=0, dAo2=0, dAcur=0, dAarg=0; u32 dATag=0;
  int dBV=0, dBSlot=0, dBo1=0, dBcur=0, dBarg=0; u32 dBTag=0;
  int ecnt=0, dcnt=0;

  // ---------------- INIT (tag 1): broadcast h0 (replicated) ----------------
  if (tid < 512) s_g[tid] = node_init[tid];
  __syncthreads();
  float cbg_r=0,cbg_z=0,bg_ni=0,bg_nh=0, bh_gr=0,bh_gz=0;
  float bn_r=0,bn_z=0,bn_nh=0, fb_r=0,fb_z=0,fb_n=0, be1w=0,bqw=0;
  if (wv < 8){
    cbg_r = s_bihg[wv*3+0]+s_bhhg[wv*3+0];
    cbg_z = s_bihg[wv*3+1]+s_bhhg[wv*3+1];
    bg_ni = s_bihg[wv*3+2]; bg_nh = s_bhhg[wv*3+2];
    bh_gr = s_bhhg[wv*3+0]; bh_gz = s_bhhg[wv*3+1];
    bn_r = s_bhhn[wv*3+0]; bn_z = s_bhhn[wv*3+1]; bn_nh = s_bhhn[wv*3+2];
    fb_r = s_bihn[wv*3+0]; fb_z = s_bihn[wv*3+1]; fb_n = s_bihn[wv*3+2];
    be1w = s_be1[wv]; bqw = s_bq[wv];
    const float* wr = w_nip + (long)d*512;
    float4 wa = *(const float4*)&wr[lane*8], wb2 = *(const float4*)&wr[lane*8+4];
    float4 xa = *(float4*)&s_g[lane*8], xb = *(float4*)&s_g[lane*8+4];
    float h0d = wred(dot4f(wa,xa)+dot4f(wb2,xb)) + b_nip[d];
    if (lane == 0){
      u64 atom = (1ull<<32) | f2u(h0d);
      #pragma unroll
      for (int c = 0; c < NCOPY; ++c) gst64(&Xh[(size_t)c*512 + d], atom);
    }
  }
  u32 ph = 2;

  float gi0r=0,gi0z=0,gi0n=0, ghn0r=0,ghn0z=0,ghn0n=0;  // caches of *@h0
  int cur = -1, have_se = 0;
  bool first_an = true;

  // ---------------- main sequential scan ----------------
  for (int t = 0; t < LSEQ; ++t){
    int a = actions[t];
    if (a == 1) continue;                    // ADD_EDGE fused into its CD phase
    if (a == 3){ have_se = 1; continue; }    // STOP_EDGE fused into next AN / drain
    if (a < 0 || a >= 4) continue;

    int t1 = (t+1 < LSEQ) ? actions[t+1] : -1;
    int nxt = (t1 == 1);
    int i2 = (t+2 < LSEQ) ? t+2 : LSEQ-1;
    int chn = nxt ? argseq[i2] : 0;          // lookahead: next edge's destination

    if (a == 0){ // ======== ADD_NODE (1 phase; absorbs pending STOP_EDGE) ========
      int eslot = ecnt & 3;
      if (first_an){
        if (tid < 512){ u64 v = pollt(&Xh[(size_t)cpy*512 + tid], 1u); s_h0[tid] = u2f((u32)v); s_g[tid] = graph0[tid]; }
      } else {
        u32 gtag = ph-1; int gpar = gtag & 1;
        if (tid < 512){ u64 v = pollt(&Xng[((size_t)(gpar*NCOPY+cpy)*512+tid)*2+1], gtag); s_g[tid] = u2f((u32)v); }
      }
      __syncthreads();
      RUN_JOBS();
      if (wv < 8){
        float4 xg_a = *(float4*)&s_g[lane*8], xg_b = *(float4*)&s_g[lane*8+4];
        float4 xc_a = *(float4*)&s_curv[lane*8], xc_b = *(float4*)&s_curv[lane*8+4];
        const u32* Whg = (const u32*)s_whhg;
        if (first_an){
          float4 xh_a = *(float4*)&s_h0[lane*8], xh_b = *(float4*)&s_h0[lane*8+4];
          const u32* Wig = (const u32*)s_wihg; const u32* Wn = (const u32*)s_whhn;
          gi0r = wred(dot8p(*(const uint4*)&Wig[(wv*3+0)*256+lane*4], xh_a,xh_b)) + s_bihg[wv*3+0];
          gi0z = wred(dot8p(*(const uint4*)&Wig[(wv*3+1)*256+lane*4], xh_a,xh_b)) + s_bihg[wv*3+1];
          gi0n = wred(dot8p(*(const uint4*)&Wig[(wv*3+2)*256+lane*4], xh_a,xh_b)) + s_bihg[wv*3+2];
          ghn0r = wred(dot8p(*(const uint4*)&Wn[(wv*3+0)*256+lane*4], xh_a,xh_b)) + bn_r;
          ghn0z = wred(dot8p(*(const uint4*)&Wn[(wv*3+1)*256+lane*4], xh_a,xh_b)) + bn_z;
          ghn0n = wred(dot8p(*(const uint4*)&Wn[(wv*3+2)*256+lane*4], xh_a,xh_b)) + bn_nh;
        }
        { // g' = GRU_g(h0, g): FIRST — the serial cross-block chain
          float ghr = wred(dot8p(*(const uint4*)&Whg[(wv*3+0)*256+lane*4], xg_a,xg_b)) + bh_gr;
          float ghz = wred(dot8p(*(const uint4*)&Whg[(wv*3+1)*256+lane*4], xg_a,xg_b)) + bh_gz;
          float ghn = wred(dot8p(*(const uint4*)&Whg[(wv*3+2)*256+lane*4], xg_a,xg_b)) + bg_nh;
          float r_ = sigm(gi0r + ghr), z_ = sigm(gi0z + ghz);
          float n_ = tanhf(gi0n + r_*ghn);
          float gv = (1.f-z_)*n_ + z_*s_g[d];
          if (lane == 0) FIRE_NG(ph&1, 1, gv);
        }
        float fr=0.f, fz=0.f, fn=0.f;
        if (cur >= 0){ // freeze prev node BEFORE lookahead read (block-local caches)
          const u32* Win = (const u32*)s_wihn;
          fr = wred(dot8p(*(const uint4*)&Win[(wv*3+0)*256+lane*4], xc_a,xc_b)) + fb_r;
          fz = wred(dot8p(*(const uint4*)&Win[(wv*3+1)*256+lane*4], xc_a,xc_b)) + fb_z;
          fn = wred(dot8p(*(const uint4*)&Win[(wv*3+2)*256+lane*4], xc_a,xc_b)) + fb_n;
          float kv;
          {
            const float* wkr = w_k + (long)d*512;
            float4 ka = *(const float4*)&wkr[lane*8], kb2 = *(const float4*)&wkr[lane*8+4];
            kv = wred(dot4f(ka,xc_a)+dot4f(kb2,xc_b));
          }
          if (lane == 0){
            s_gin[cur*24+wv*3+0] = f2bf(fr); s_gin[cur*24+wv*3+1] = f2bf(fz); s_gin[cur*24+wv*3+2] = f2bf(fn);
            s_kloc[wv*128 + cur] = kv;
          }
        }
        if (nxt){ // ncur1 = GRU_n(chosen1, h0); forward freeze regs if chn==cur
          float gr = (chn == cur && cur >= 0) ? fr : bf2f(s_gin[chn*24+wv*3+0]);
          float gz = (chn == cur && cur >= 0) ? fz : bf2f(s_gin[chn*24+wv*3+1]);
          float gn = (chn == cur && cur >= 0) ? fn : bf2f(s_gin[chn*24+wv*3+2]);
          float r2 = sigm(gr + ghn0r), z2 = sigm(gz + ghn0z);
          float n2 = tanhf(gn + r2*ghn0n);
          float nv = (1.f-z2)*n2 + z2*s_h0[d];
          if (lane == 0) FIRE_NG(ph&1, 0, nv);
        }
        if (have_se){ // deferred STOP_EDGE partials
          const u32* Re = (const u32*)s_we1 + wv*512;
          float pe = dot8p(*(const uint4*)&Re[lane*4], xg_a,xg_b) + dot8p(*(const uint4*)&Re[256+lane*4], xc_a,xc_b);
          float hv = fmaxf(wred(pe) + be1w, 0.f);
          if (lane == 0){ s_red[wv*2+0] = hv*we2_0; s_red[wv*2+1] = hv*we2_1; }
        }
      }
      __syncthreads();
      if (have_se && tid == 0){
        float p0 = 0.f, p1 = 0.f;
        #pragma unroll
        for (int i = 0; i < 8; ++i){ p0 += s_red[i*2]; p1 += s_red[i*2+1]; }
        gst64(&XE[eslot*64 + b], ((u64)ph<<32) | (u32)f2bf(p0) | ((u32)f2bf(p1)<<16));
      }
      if (tid < 512) s_curv[tid] = s_h0[tid];
      SHIFT_JOBS();
      if (have_se){ aeV=1; aeSlot=eslot; aeSel=1; aeOwn=ecnt&63; aeTag=ph; ecnt++; }
      have_se = 0; first_an = false;
      cur += 1; ph += 1;
    }
    else { // ======== CHOOSE_DEST: ONE phase (AE fused; ncur pipelined ahead) ========
      int arg = argseq[t];
      int eslot = ecnt & 3, dslot = dcnt & 1;
      {
        u32 gtag = ph-1; int gpar = gtag & 1;
        if (tid < 512){
          u64 v0, v1; int n = 0;
          const u64* p = &Xng[((size_t)(gpar*NCOPY+cpy)*512 + tid)*2];
          do { v0 = gld64(p); v1 = gld64(p+1); }
          while ((((u32)(v0>>32) != gtag) || ((u32)(v1>>32) != gtag)) && ++n < (1<<20));
          s_nc[tid] = u2f((u32)v0); s_g[tid] = u2f((u32)v1);
        }
      }
      __syncthreads();
      RUN_JOBS();
      if (wv < 8){
        float4 xn_a = *(float4*)&s_nc[lane*8], xn_b = *(float4*)&s_nc[lane*8+4];
        float4 xg_a = *(float4*)&s_g[lane*8],  xg_b = *(float4*)&s_g[lane*8+4];
        float4 xc_a = *(float4*)&s_curv[lane*8], xc_b = *(float4*)&s_curv[lane*8+4];
        const u32* Wn = (const u32*)s_whhn; const u32* Wig = (const u32*)s_wihg; const u32* Whg = (const u32*)s_whhg;
        { // 1) fire g_j FIRST (critical cross-block chain); r/z partials pre-combined
          float pr = dot8p(*(const uint4*)&Wig[(wv*3+0)*256+lane*4], xn_a,xn_b)
                   + dot8p(*(const uint4*)&Whg[(wv*3+0)*256+lane*4], xg_a,xg_b);
          float pz = dot8p(*(const uint4*)&Wig[(wv*3+1)*256+lane*4], xn_a,xn_b)
                   + dot8p(*(const uint4*)&Whg[(wv*3+1)*256+lane*4], xg_a,xg_b);
          float r_ = sigm(wred(pr) + cbg_r);
          float z_ = sigm(wred(pz) + cbg_z);
          float gin_ = wred(dot8p(*(const uint4*)&Wig[(wv*3+2)*256+lane*4], xn_a,xn_b)) + bg_ni;
          float ghn_ = wred(dot8p(*(const uint4*)&Whg[(wv*3+2)*256+lane*4], xg_a,xg_b)) + bg_nh;
          float n_ = tanhf(gin_ + r_*ghn_);
          float gv = (1.f-z_)*n_ + z_*s_g[d];
          if (lane == 0) FIRE_NG(ph&1, 1, gv);
        }
        if (nxt){ // 2) fire ncur_{j+1} = GRU_n(chosen_{j+1}, ncur_j)
          float ghr = wred(dot8p(*(const uint4*)&Wn[(wv*3+0)*256+lane*4], xn_a,xn_b)) + bn_r;
          float ghz = wred(dot8p(*(const uint4*)&Wn[(wv*3+1)*256+lane*4], xn_a,xn_b)) + bn_z;
          float ghn = wred(dot8p(*(const uint4*)&Wn[(wv*3+2)*256+lane*4], xn_a,xn_b)) + bn_nh;
          float gr = bf2f(s_gin[chn*24+wv*3+0]), gz = bf2f(s_gin[chn*24+wv*3+1]), gn = bf2f(s_gin[chn*24+wv*3+2]);
          float r_ = sigm(gr+ghr), z_ = sigm(gz+ghz);
          float n_ = tanhf(gn + r_*ghn);
          float nv = (1.f-z_)*n_ + z_*s_nc[d];
          if (lane == 0) FIRE_NG(ph&1, 0, nv);
        }
        { // 3) q_j and AE e-logit partials from (g_{j-1}, curv_{j-1})
          const u32* Rq = (const u32*)s_wq + wv*512;
          float pq = dot8p(*(const uint4*)&Rq[lane*4], xg_a,xg_b) + dot8p(*(const uint4*)&Rq[256+lane*4], xc_a,xc_b);
          float qd = wred(pq) + bqw;
          const u32* Re = (const u32*)s_we1 + wv*512;
          float pe = dot8p(*(const uint4*)&Re[lane*4], xg_a,xg_b) + dot8p(*(const uint4*)&Re[256+lane*4], xc_a,xc_b);
          float hv = fmaxf(wred(pe) + be1w, 0.f);
          if (lane == 0){ s_q8[wv] = qd; s_red[wv*2+0] = hv*we2_0; s_red[wv*2+1] = hv*we2_1; }
        }
      }
      __syncthreads();
      if (tid < 64){ // dest-logit partials: local k slices x local q dims
        float pl0 = 0.f, pl1 = 0.f;
        #pragma unroll
        for (int k = 0; k < 8; ++k){
          pl0 += s_kloc[k*128 + tid]      * s_q8[k];
          pl1 += s_kloc[k*128 + tid + 64] * s_q8[k];
        }
        gst64(&XP[((size_t)(dslot*64 + tid))*64 + b],
              ((u64)ph<<32) | (u32)f2bf(pl0) | ((u32)f2bf(pl1)<<16));
      }
      if (tid == 64){
        float p0 = 0.f, p1 = 0.f;
        #pragma unroll
        for (int i = 0; i < 8; ++i){ p0 += s_red[i*2]; p1 += s_red[i*2+1]; }
        gst64(&XE[eslot*64 + b], ((u64)ph<<32) | (u32)f2bf(p0) | ((u32)f2bf(p1)<<16));
      }
      if (tid < 512) s_curv[tid] = s_nc[tid];
      SHIFT_JOBS();
      aeV=1; aeSlot=eslot; aeSel=0; aeOwn=ecnt&63; aeTag=ph; ecnt++;
      dAV=1; dASlot=dslot; dAo1=(2*dcnt)&63; dAo2=(2*dcnt+1)&63; dAcur=cur; dAarg=arg; dATag=ph;
      dcnt++;
      ph += 1;
    }
  }

  // ---------------- drain: V1 (final SE partials + last stage-B), V2 (collect) ----------------
  {
    int eslot = ecnt & 3;
    u32 gtag = ph-1; int gpar = gtag & 1;
    if (tid < 512){ u64 v = pollt(&Xng[((size_t)(gpar*NCOPY+cpy)*512+tid)*2+1], gtag); s_g[tid] = u2f((u32)v); }
    __syncthreads();
    RUN_JOBS();                               // jobs due this phase
    if (have_se && wv < 8){
      float4 xg_a = *(float4*)&s_g[lane*8], xg_b = *(float4*)&s_g[lane*8+4];
      float4 xc_a = *(float4*)&s_curv[lane*8], xc_b = *(float4*)&s_curv[lane*8+4];
      const u32* Re = (const u32*)s_we1 + wv*512;
      float pe = dot8p(*(const uint4*)&Re[lane*4], xg_a,xg_b) + dot8p(*(const uint4*)&Re[256+lane*4], xc_a,xc_b);
      float hv = fmaxf(wred(pe) + be1w, 0.f);
      if (lane == 0){ s_red[wv*2] = hv*we2_0; s_red[wv*2+1] = hv*we2_1; }
    }
    __syncthreads();
    if (have_se && tid == 0){
      float p0 = 0.f, p1 = 0.f;
      #pragma unroll
      for (int i = 0; i < 8; ++i){ p0 += s_red[i*2]; p1 += s_red[i*2+1]; }
      gst64(&XE[eslot*64 + b], ((u64)ph<<32) | (u32)f2bf(p0) | ((u32)f2bf(p1)<<16));
    }
    SHIFT_JOBS();
    RUN_JOBS();                               // stage-B of the last CHOOSE_DEST
    if (wv == 8){
      if (have_se && b == 0){
        u64 v = pollt(&XE[eslot*64 + lane], ph);
        float p0 = wredsh(bf2f((u16)(v & 0xffff)));
        float p1 = wredsh(bf2f((u16)((v>>16) & 0xffff)));
        if (lane == 0){
          float l0 = p0 + be2_0, l1 = p1 + be2_1;
          float m = fmaxf(l0, l1);
          nllw += m + logf(__expf(l0-m) + __expf(l1-m)) - l1;   // STOP_EDGE selects idx 1
        }
      }
      if (lane == 0) gst64(&XN[b], (0xFFFFull<<32) | f2u(nllw));
      if (b == 0){
        u64 v = pollt(&XN[lane], 0xFFFFu);
        float tot = wredsh(u2f((u32)v));
        if (lane == 0) out[0] = tot;
      }
    }
  }
}

extern "C" void kernel_launch(void* const* d_in, const int* in_sizes, int n_in,
                              void* d_out, int out_size, void* d_ws, size_t ws_size,
                              hipStream_t stream) {
  (void)in_sizes; (void)n_in; (void)out_size; (void)ws_size;
  // zero all tag-atom regions (57920 u64) — exact-match tags then poison/replay-safe
  hipMemsetAsync(d_ws, 0, 463360, stream);
  hipFuncSetAttribute((const void*)dgmg_kernel,
                      hipFuncAttributeMaxDynamicSharedMemorySize, SMEM_BYTES);
  dgmg_kernel<<<NBLK, NTHR, SMEM_BYTES, stream>>>(
      (const int*)d_in[0], (const int*)d_in[1],
      (const float*)d_in[2], (const float*)d_in[3], (const float*)d_in[4],
      (const float*)d_in[5], (const float*)d_in[6],
      (const float*)d_in[7], (const float*)d_in[8],
      (const float*)d_in[9], (const float*)d_in[10],
      (const float*)d_in[11],                      /* w_k ; b_k unused (cancels) */
      (const float*)d_in[13], (const float*)d_in[14],
      (const float*)d_in[15], (const float*)d_in[16],
      (const float*)d_in[17], (const float*)d_in[18],
      (const float*)d_in[19], (const float*)d_in[20],
      (const float*)d_in[21],
      (float*)d_out, (unsigned char*)d_ws);
}

// Round 13
// 1112.314 us; speedup vs baseline: 1.3855x; 1.3855x over previous
//
#include <hip/hip_runtime.h>
#include <math.h>

#define NBLK 64
#define NTHR 576        // 9 waves: 8 compute + 1 fire/job wave
#define LSEQ 1024

typedef unsigned int u32;
typedef unsigned short u16;
typedef unsigned long long u64;

// ---------------- scalar helpers ----------------
__device__ __forceinline__ float bf2f(u16 u){ union{u32 i;float f;}v; v.i=(u32)u<<16; return v.f; }
__device__ __forceinline__ u16 f2bf(float f){ union{float f;u32 i;}v; v.f=f; u32 x=v.i;
  return (u16)((x + 0x7fffu + ((x>>16)&1u)) >> 16); }
__device__ __forceinline__ float u2f(u32 u){ union{u32 i;float f;}v; v.i=u; return v.f; }
__device__ __forceinline__ u32  f2u(float f){ union{float f;u32 i;}v; v.f=f; return v.i; }
__device__ __forceinline__ float sigm(float x){ return 1.f/(1.f+__expf(-x)); }

// coherent (agent-scope) 8B atoms: (tag<<32)|payload
__device__ __forceinline__ u64 gld64(const u64* p){ return __hip_atomic_load(const_cast<u64*>(p), __ATOMIC_RELAXED, __HIP_MEMORY_SCOPE_AGENT); }
__device__ __forceinline__ void gst64(u64* p, u64 v){ __hip_atomic_store(p, v, __ATOMIC_RELAXED, __HIP_MEMORY_SCOPE_AGENT); }
__device__ __forceinline__ u64 pollt(const u64* p, u32 tag){
  u64 v; int n = 0;
  do { v = gld64(p); } while ((u32)(v>>32) != tag && ++n < (1<<20));
  return v;
}

// ---------------- reductions ----------------
// DPP full-wave(64) sum; result uniform. VALU-only.
__device__ __forceinline__ float wred(float a){
  a += __int_as_float(__builtin_amdgcn_update_dpp(0, __float_as_int(a), 0x111, 0xf, 0xf, true));
  a += __int_as_float(__builtin_amdgcn_update_dpp(0, __float_as_int(a), 0x112, 0xf, 0xf, true));
  a += __int_as_float(__builtin_amdgcn_update_dpp(0, __float_as_int(a), 0x114, 0xf, 0xf, true));
  a += __int_as_float(__builtin_amdgcn_update_dpp(0, __float_as_int(a), 0x118, 0xf, 0xf, true));
  a += __int_as_float(__builtin_amdgcn_update_dpp(0, __float_as_int(a), 0x142, 0xa, 0xf, true));
  a += __int_as_float(__builtin_amdgcn_update_dpp(0, __float_as_int(a), 0x143, 0xc, 0xf, true));
  return __int_as_float(__builtin_amdgcn_readlane(__float_as_int(a), 63));
}
__device__ __forceinline__ float wredsh(float a){
  #pragma unroll
  for (int off = 32; off; off >>= 1) a += __shfl_xor(a, off);
  return a;
}
__device__ __forceinline__ float wredmaxsh(float a){
  #pragma unroll
  for (int off = 32; off; off >>= 1) a = fmaxf(a, __shfl_xor(a, off));
  return a;
}

// ---------------- packed dot helpers ----------------
__device__ __forceinline__ float dot8p(uint4 w, float4 a, float4 b2){
  float s;
  s  = u2f(w.x<<16)*a.x  + u2f(w.x&0xffff0000u)*a.y;
  s += u2f(w.y<<16)*a.z  + u2f(w.y&0xffff0000u)*a.w;
  s += u2f(w.z<<16)*b2.x + u2f(w.z&0xffff0000u)*b2.y;
  s += u2f(w.w<<16)*b2.z + u2f(w.w&0xffff0000u)*b2.w;
  return s;
}
__device__ __forceinline__ float dot4f(float4 w, float4 x){
  return w.x*x.x + w.y*x.y + w.z*x.z + w.w*x.w;
}
__device__ __forceinline__ uint4 pk8(float4 a, float4 b2){
  uint4 r;
  r.x = (u32)f2bf(a.x)  | ((u32)f2bf(a.y)<<16);
  r.y = (u32)f2bf(a.z)  | ((u32)f2bf(a.w)<<16);
  r.z = (u32)f2bf(b2.x) | ((u32)f2bf(b2.y)<<16);
  r.w = (u32)f2bf(b2.z) | ((u32)f2bf(b2.w)<<16);
  return r;
}

#define SMEM_BYTES 150048

// wave-8 deferred log-softmax jobs (round-robin across blocks, off critical path)
#define RUN_JOBS() do { \
  if (wv == 8){ \
    if (dBV && b == dBo1){ \
      u64 v_ = pollt(XS + dBSlot*64 + lane, dBTag); \
      float x0 = sA0 + bf2f((u16)(v_ & 0xffff)); \
      float x1 = sA1 + bf2f((u16)((v_>>16) & 0xffff)); \
      x0 = (lane < dBcur) ? x0 : -__builtin_inff(); \
      x1 = (lane + 64 < dBcur) ? x1 : -__builtin_inff(); \
      float m_ = wredmaxsh(fmaxf(x0, x1)); \
      float s_ = wredsh(__expf(x0 - m_) + __expf(x1 - m_)); \
      float la_ = (dBarg < 64) ? __shfl(x0, dBarg) : __shfl(x1, dBarg - 64); \
      if (lane == 0) nllw += (m_ + logf(s_)) - la_; \
    } \
    if (dAV && (b == dAo1 || b == dAo2)){ \
      const u64* P_ = XP + ((size_t)(dASlot*64 + lane))*64 + ((b == dAo2) ? 32 : 0); \
      float h0_ = 0.f, h1_ = 0.f; \
      for (int c_ = 0; c_ < 2; ++c_){ \
        u64 vv_[16]; int bad_; int nn_ = 0; \
        do { bad_ = 0; \
          _Pragma("unroll") for (int j_ = 0; j_ < 16; ++j_) vv_[j_] = gld64(P_ + c_*16 + j_); \
          _Pragma("unroll") for (int j_ = 0; j_ < 16; ++j_) bad_ |= ((u32)(vv_[j_]>>32) != dATag); \
        } while (bad_ && ++nn_ < (1<<20)); \
        _Pragma("unroll") for (int j_ = 0; j_ < 16; ++j_){ \
          h0_ += bf2f((u16)(vv_[j_] & 0xffff)); h1_ += bf2f((u16)((vv_[j_]>>16) & 0xffff)); } \
      } \
      if (b == dAo2) gst64(XS + dASlot*64 + lane, ((u64)dATag<<32) | (u32)f2bf(h0_) | ((u32)f2bf(h1_)<<16)); \
      else { sA0 = h0_; sA1 = h1_; } \
    } \
    if (aeV && b == aeOwn){ \
      u64 v_ = pollt(XE + aeSlot*64 + lane, aeTag); \
      float p0_ = wredsh(bf2f((u16)(v_ & 0xffff))); \
      float p1_ = wredsh(bf2f((u16)((v_>>16) & 0xffff))); \
      if (lane == 0){ \
        float l0_ = p0_ + be2_0, l1_ = p1_ + be2_1; \
        float m_ = fmaxf(l0_, l1_); \
        nllw += m_ + logf(__expf(l0_-m_) + __expf(l1_-m_)) - (aeSel ? l1_ : l0_); \
      } \
    } \
  } \
} while(0)

#define SHIFT_JOBS() do { \
  dBV = dAV; dBSlot = dASlot; dBo1 = dAo1; dBTag = dATag; dBcur = dAcur; dBarg = dAarg; \
  dAV = 0; aeV = 0; \
} while(0)

__global__ void __launch_bounds__(NTHR, 1)
dgmg_kernel(const int* __restrict__ actions, const int* __restrict__ argseq,
            const float* __restrict__ node_init, const float* __restrict__ w_nip, const float* __restrict__ b_nip,
            const float* __restrict__ w_e1, const float* __restrict__ b_e1,
            const float* __restrict__ w_e2, const float* __restrict__ b_e2,
            const float* __restrict__ w_q, const float* __restrict__ b_q,
            const float* __restrict__ w_k,
            const float* __restrict__ wih_n, const float* __restrict__ whh_n,
            const float* __restrict__ bih_n, const float* __restrict__ bhh_n,
            const float* __restrict__ wih_g, const float* __restrict__ whh_g,
            const float* __restrict__ bih_g, const float* __restrict__ bhh_g,
            const float* __restrict__ graph0,
            float* __restrict__ out, unsigned char* __restrict__ ws)
{
  extern __shared__ unsigned char smem[];
  u16* s_wihg = (u16*)smem;                 // [24][512] packed bf16
  u16* s_whhg = s_wihg + 24*512;
  u16* s_wihn = s_whhg + 24*512;
  u16* s_whhn = s_wihn + 24*512;
  u16* s_we1  = s_whhn + 24*512;            // [8][1024]
  u16* s_wq   = s_we1 + 8*1024;             // [8][1024]
  float* s_g    = (float*)(s_wq + 8*1024);  // staged graph vector
  float* s_nc   = s_g + 512;                // staged ncur (current node, post-GRU_n)
  float* s_curv = s_nc + 512;               // current node vector pre-update
  float* s_h0   = s_curv + 512;             // fresh-node embedding
  float* s_kloc = s_h0 + 512;               // [8][128] transposed k-cache: [dim][node]
  float* s_bihg = s_kloc + 1024;            // [24]
  float* s_bhhg = s_bihg + 24;
  float* s_bihn = s_bhhg + 24;
  float* s_bhhn = s_bihn + 24;
  float* s_be1  = s_bhhn + 24;              // [8]
  float* s_bq   = s_be1 + 8;                // [8]
  float* s_q8   = s_bq + 8;                 // [8]
  float* s_red  = s_q8 + 8;                 // [16]
  u16*   s_gin  = (u16*)(s_red + 16);       // [128][24] gi_n freeze cache (bf16, bias incl.)

  const int b = blockIdx.x, tid = threadIdx.x;
  const int wv = tid >> 6, lane = tid & 63;
  const int d = b*8 + ((wv < 8) ? wv : 0);

  // workspace: tagged u64 atoms
  u64* Xng = (u64*)ws;         // [2][512][2]: per dim {ncur, g} adjacent (same cache line)
  u64* Xh  = Xng + 2048;       // [512] h0 broadcast
  u64* XE  = Xh + 512;         // [4][64] edge-logit partials (2xbf16)
  u64* XP  = XE + 256;         // [4][64][64] dest-logit partials
  u64* XS  = XP + 16384;       // [4][64] dest half-sums
  u64* XN  = XS + 256;         // [64] final nll pieces

  // ---------------- init: biases + packed bf16 weight slices ----------------
  if (tid < 24){
    int ld = tid/3, gt = tid%3;
    int row = gt*512 + b*8 + ld;
    s_bihg[tid] = bih_g[row]; s_bhhg[tid] = bhh_g[row];
    s_bihn[tid] = bih_n[row]; s_bhhn[tid] = bhh_n[row];
  }
  if (tid < 8){ s_be1[tid] = b_e1[b*8+tid]; s_bq[tid] = b_q[b*8+tid]; }

  for (int r = wv; r < 24; r += 9){           // all 9 waves pack
    int ld = r/3, gt = r%3;
    long grow = (long)(gt*512 + b*8 + ld) * 512;
    float4 a0, a1;
    a0 = *(const float4*)&wih_g[grow + lane*8]; a1 = *(const float4*)&wih_g[grow + lane*8 + 4];
    *(uint4*)&s_wihg[r*512 + lane*8] = pk8(a0, a1);
    a0 = *(const float4*)&whh_g[grow + lane*8]; a1 = *(const float4*)&whh_g[grow + lane*8 + 4];
    *(uint4*)&s_whhg[r*512 + lane*8] = pk8(a0, a1);
    a0 = *(const float4*)&wih_n[grow + lane*8]; a1 = *(const float4*)&wih_n[grow + lane*8 + 4];
    *(uint4*)&s_wihn[r*512 + lane*8] = pk8(a0, a1);
    a0 = *(const float4*)&whh_n[grow + lane*8]; a1 = *(const float4*)&whh_n[grow + lane*8 + 4];
    *(uint4*)&s_whhn[r*512 + lane*8] = pk8(a0, a1);
  }
  if (wv < 8){
    long grow = (long)(b*8 + wv) * 1024;
    #pragma unroll
    for (int h = 0; h < 2; ++h){
      float4 a0 = *(const float4*)&w_e1[grow + h*512 + lane*8];
      float4 a1 = *(const float4*)&w_e1[grow + h*512 + lane*8 + 4];
      *(uint4*)&s_we1[wv*1024 + h*512 + lane*8] = pk8(a0, a1);
      float4 q0 = *(const float4*)&w_q[grow + h*512 + lane*8];
      float4 q1 = *(const float4*)&w_q[grow + h*512 + lane*8 + 4];
      *(uint4*)&s_wq[wv*1024 + h*512 + lane*8] = pk8(q0, q1);
    }
  }
  float we2_0 = w_e2[d], we2_1 = w_e2[512+d];
  float be2_0 = b_e2[0], be2_1 = b_e2[1];
  float nllw = 0.f, sA0 = 0.f, sA1 = 0.f;

  // job state
  int aeV=0, aeSlot=0, aeSel=0, aeOwn=0; u32 aeTag=0;
  int dAV=0, dASlot=0, dAo1=0, dAo2=0, dAcur=0, dAarg=0; u32 dATag=0;
  int dBV=0, dBSlot=0, dBo1=0, dBcur=0, dBarg=0; u32 dBTag=0;
  int ecnt=0, dcnt=0;

  // ---------------- INIT (tag 1): broadcast h0 ----------------
  if (tid < 512) s_g[tid] = node_init[tid];
  __syncthreads();
  // register-cache per-wave bias constants
  float cbg_r=0,cbg_z=0,bg_ni=0,bg_nh=0, bh_gr=0,bh_gz=0;
  float bn_r=0,bn_z=0,bn_nh=0, fb_r=0,fb_z=0,fb_n=0, be1w=0,bqw=0;
  if (wv < 8){
    cbg_r = s_bihg[wv*3+0]+s_bhhg[wv*3+0];
    cbg_z = s_bihg[wv*3+1]+s_bhhg[wv*3+1];
    bg_ni = s_bihg[wv*3+2]; bg_nh = s_bhhg[wv*3+2];
    bh_gr = s_bhhg[wv*3+0]; bh_gz = s_bhhg[wv*3+1];
    bn_r = s_bhhn[wv*3+0]; bn_z = s_bhhn[wv*3+1]; bn_nh = s_bhhn[wv*3+2];
    fb_r = s_bihn[wv*3+0]; fb_z = s_bihn[wv*3+1]; fb_n = s_bihn[wv*3+2];
    be1w = s_be1[wv]; bqw = s_bq[wv];
    const float* wr = w_nip + (long)d*512;
    float4 wa = *(const float4*)&wr[lane*8], wb2 = *(const float4*)&wr[lane*8+4];
    float4 xa = *(float4*)&s_g[lane*8], xb = *(float4*)&s_g[lane*8+4];
    float h0d = wred(dot4f(wa,xa)+dot4f(wb2,xb)) + b_nip[d];
    if (lane == 0) gst64(&Xh[d], (1ull<<32) | f2u(h0d));
  }
  u32 ph = 2;

  float gi0r=0,gi0z=0,gi0n=0, ghn0r=0,ghn0z=0,ghn0n=0;  // caches of *@h0
  int cur = -1, have_se = 0;
  bool first_an = true;

  // ---------------- main sequential scan ----------------
  for (int t = 0; t < LSEQ; ++t){
    int a = actions[t];
    if (a == 1) continue;                    // ADD_EDGE fused into its CD phase
    if (a == 3){ have_se = 1; continue; }    // STOP_EDGE fused into next AN / drain
    if (a < 0 || a >= 4) continue;

    int t1 = (t+1 < LSEQ) ? actions[t+1] : -1;
    int nxt = (t1 == 1);
    int i2 = (t+2 < LSEQ) ? t+2 : LSEQ-1;
    int chn = nxt ? argseq[i2] : 0;          // lookahead: next edge's destination

    if (a == 0){ // ======== ADD_NODE (1 phase; absorbs pending STOP_EDGE) ========
      int eslot = ecnt & 3;
      if (first_an){
        if (tid < 512){ u64 v = pollt(&Xh[tid], 1u); s_h0[tid] = u2f((u32)v); s_g[tid] = graph0[tid]; }
      } else {
        u32 gtag = ph-1; int gpar = gtag & 1;
        if (tid < 512){ u64 v = pollt(&Xng[(gpar*512+tid)*2+1], gtag); s_g[tid] = u2f((u32)v); }
      }
      __syncthreads();
      RUN_JOBS();
      if (wv < 8){
        float4 xg_a = *(float4*)&s_g[lane*8], xg_b = *(float4*)&s_g[lane*8+4];
        float4 xc_a = *(float4*)&s_curv[lane*8], xc_b = *(float4*)&s_curv[lane*8+4];
        const u32* Whg = (const u32*)s_whhg;
        if (first_an){
          float4 xh_a = *(float4*)&s_h0[lane*8], xh_b = *(float4*)&s_h0[lane*8+4];
          const u32* Wig = (const u32*)s_wihg; const u32* Wn = (const u32*)s_whhn;
          gi0r = wred(dot8p(*(const uint4*)&Wig[(wv*3+0)*256+lane*4], xh_a,xh_b)) + s_bihg[wv*3+0];
          gi0z = wred(dot8p(*(const uint4*)&Wig[(wv*3+1)*256+lane*4], xh_a,xh_b)) + s_bihg[wv*3+1];
          gi0n = wred(dot8p(*(const uint4*)&Wig[(wv*3+2)*256+lane*4], xh_a,xh_b)) + s_bihg[wv*3+2];
          ghn0r = wred(dot8p(*(const uint4*)&Wn[(wv*3+0)*256+lane*4], xh_a,xh_b)) + bn_r;
          ghn0z = wred(dot8p(*(const uint4*)&Wn[(wv*3+1)*256+lane*4], xh_a,xh_b)) + bn_z;
          ghn0n = wred(dot8p(*(const uint4*)&Wn[(wv*3+2)*256+lane*4], xh_a,xh_b)) + bn_nh;
        }
        { // g' = GRU_g(h0, g): FIRST — the serial cross-block chain
          float ghr = wred(dot8p(*(const uint4*)&Whg[(wv*3+0)*256+lane*4], xg_a,xg_b)) + bh_gr;
          float ghz = wred(dot8p(*(const uint4*)&Whg[(wv*3+1)*256+lane*4], xg_a,xg_b)) + bh_gz;
          float ghn = wred(dot8p(*(const uint4*)&Whg[(wv*3+2)*256+lane*4], xg_a,xg_b)) + bg_nh;
          float r_ = sigm(gi0r + ghr), z_ = sigm(gi0z + ghz);
          float n_ = tanhf(gi0n + r_*ghn);
          if (lane == 0) gst64(&Xng[((ph&1)*512+d)*2+1], ((u64)ph<<32) | f2u((1.f-z_)*n_ + z_*s_g[d]));  // FIRE
        }
        float fr=0.f, fz=0.f, fn=0.f;
        if (cur >= 0){ // freeze prev node BEFORE lookahead read (block-local caches)
          const u32* Win = (const u32*)s_wihn;
          fr = wred(dot8p(*(const uint4*)&Win[(wv*3+0)*256+lane*4], xc_a,xc_b)) + fb_r;
          fz = wred(dot8p(*(const uint4*)&Win[(wv*3+1)*256+lane*4], xc_a,xc_b)) + fb_z;
          fn = wred(dot8p(*(const uint4*)&Win[(wv*3+2)*256+lane*4], xc_a,xc_b)) + fb_n;
          float kv;
          {
            const float* wkr = w_k + (long)d*512;
            float4 ka = *(const float4*)&wkr[lane*8], kb2 = *(const float4*)&wkr[lane*8+4];
            kv = wred(dot4f(ka,xc_a)+dot4f(kb2,xc_b));
          }
          if (lane == 0){
            s_gin[cur*24+wv*3+0] = f2bf(fr); s_gin[cur*24+wv*3+1] = f2bf(fz); s_gin[cur*24+wv*3+2] = f2bf(fn);
            s_kloc[wv*128 + cur] = kv;
          }
        }
        if (nxt){ // ncur1 = GRU_n(chosen1, h0); forward freeze regs if chn==cur
          float gr = (chn == cur && cur >= 0) ? fr : bf2f(s_gin[chn*24+wv*3+0]);
          float gz = (chn == cur && cur >= 0) ? fz : bf2f(s_gin[chn*24+wv*3+1]);
          float gn = (chn == cur && cur >= 0) ? fn : bf2f(s_gin[chn*24+wv*3+2]);
          float r2 = sigm(gr + ghn0r), z2 = sigm(gz + ghn0z);
          float n2 = tanhf(gn + r2*ghn0n);
          if (lane == 0) gst64(&Xng[((ph&1)*512+d)*2], ((u64)ph<<32) | f2u((1.f-z2)*n2 + z2*s_h0[d]));
        }
        if (have_se){ // deferred STOP_EDGE partials
          const u32* Re = (const u32*)s_we1 + wv*512;
          float pe = dot8p(*(const uint4*)&Re[lane*4], xg_a,xg_b) + dot8p(*(const uint4*)&Re[256+lane*4], xc_a,xc_b);
          float hv = fmaxf(wred(pe) + be1w, 0.f);
          if (lane == 0){ s_red[wv*2+0] = hv*we2_0; s_red[wv*2+1] = hv*we2_1; }
        }
      }
      __syncthreads();
      if (have_se && tid == 0){
        float p0 = 0.f, p1 = 0.f;
        #pragma unroll
        for (int i = 0; i < 8; ++i){ p0 += s_red[i*2]; p1 += s_red[i*2+1]; }
        gst64(&XE[eslot*64 + b], ((u64)ph<<32) | (u32)f2bf(p0) | ((u32)f2bf(p1)<<16));
      }
      if (tid < 512) s_curv[tid] = s_h0[tid];
      SHIFT_JOBS();
      if (have_se){ aeV=1; aeSlot=eslot; aeSel=1; aeOwn=ecnt&63; aeTag=ph; ecnt++; }
      have_se = 0; first_an = false;
      cur += 1; ph += 1;
    }
    else { // ======== CHOOSE_DEST: ONE phase (AE fused; ncur pipelined ahead) ========
      int arg = argseq[t];
      int eslot = ecnt & 3, dslot = dcnt & 1;
      {
        u32 gtag = ph-1; int gpar = gtag & 1;
        if (tid < 512){
          u64 v0, v1; int n = 0;
          const u64* p = &Xng[(gpar*512 + tid)*2];
          do { v0 = gld64(p); v1 = gld64(p+1); }
          while ((((u32)(v0>>32) != gtag) || ((u32)(v1>>32) != gtag)) && ++n < (1<<20));
          s_nc[tid] = u2f((u32)v0); s_g[tid] = u2f((u32)v1);
        }
      }
      __syncthreads();
      RUN_JOBS();
      if (wv < 8){
        float4 xn_a = *(float4*)&s_nc[lane*8], xn_b = *(float4*)&s_nc[lane*8+4];
        float4 xg_a = *(float4*)&s_g[lane*8],  xg_b = *(float4*)&s_g[lane*8+4];
        float4 xc_a = *(float4*)&s_curv[lane*8], xc_b = *(float4*)&s_curv[lane*8+4];
        const u32* Wn = (const u32*)s_whhn; const u32* Wig = (const u32*)s_wihg; const u32* Whg = (const u32*)s_whhg;
        { // 1) fire g_j FIRST (critical cross-block chain); r/z partials pre-combined
          float pr = dot8p(*(const uint4*)&Wig[(wv*3+0)*256+lane*4], xn_a,xn_b)
                   + dot8p(*(const uint4*)&Whg[(wv*3+0)*256+lane*4], xg_a,xg_b);
          float pz = dot8p(*(const uint4*)&Wig[(wv*3+1)*256+lane*4], xn_a,xn_b)
                   + dot8p(*(const uint4*)&Whg[(wv*3+1)*256+lane*4], xg_a,xg_b);
          float r_ = sigm(wred(pr) + cbg_r);
          float z_ = sigm(wred(pz) + cbg_z);
          float gin_ = wred(dot8p(*(const uint4*)&Wig[(wv*3+2)*256+lane*4], xn_a,xn_b)) + bg_ni;
          float ghn_ = wred(dot8p(*(const uint4*)&Whg[(wv*3+2)*256+lane*4], xg_a,xg_b)) + bg_nh;
          float n_ = tanhf(gin_ + r_*ghn_);
          if (lane == 0) gst64(&Xng[((ph&1)*512+d)*2+1], ((u64)ph<<32) | f2u((1.f-z_)*n_ + z_*s_g[d])); // FIRE g2
        }
        if (nxt){ // 2) fire ncur_{j+1} = GRU_n(chosen_{j+1}, ncur_j)
          float ghr = wred(dot8p(*(const uint4*)&Wn[(wv*3+0)*256+lane*4], xn_a,xn_b)) + bn_r;
          float ghz = wred(dot8p(*(const uint4*)&Wn[(wv*3+1)*256+lane*4], xn_a,xn_b)) + bn_z;
          float ghn = wred(dot8p(*(const uint4*)&Wn[(wv*3+2)*256+lane*4], xn_a,xn_b)) + bn_nh;
          float gr = bf2f(s_gin[chn*24+wv*3+0]), gz = bf2f(s_gin[chn*24+wv*3+1]), gn = bf2f(s_gin[chn*24+wv*3+2]);
          float r_ = sigm(gr+ghr), z_ = sigm(gz+ghz);
          float n_ = tanhf(gn + r_*ghn);
          if (lane == 0) gst64(&Xng[((ph&1)*512+d)*2], ((u64)ph<<32) | f2u((1.f-z_)*n_ + z_*s_nc[d])); // FIRE ncur
        }
        { // 3) q_j and AE e-logit partials from (g_{j-1}, curv_{j-1})
          const u32* Rq = (const u32*)s_wq + wv*512;
          float pq = dot8p(*(const uint4*)&Rq[lane*4], xg_a,xg_b) + dot8p(*(const uint4*)&Rq[256+lane*4], xc_a,xc_b);
          float qd = wred(pq) + bqw;
          const u32* Re = (const u32*)s_we1 + wv*512;
          float pe = dot8p(*(const uint4*)&Re[lane*4], xg_a,xg_b) + dot8p(*(const uint4*)&Re[256+lane*4], xc_a,xc_b);
          float hv = fmaxf(wred(pe) + be1w, 0.f);
          if (lane == 0){ s_q8[wv] = qd; s_red[wv*2+0] = hv*we2_0; s_red[wv*2+1] = hv*we2_1; }
        }
      }
      __syncthreads();
      if (tid < 64){ // dest-logit partials: local k slices x local q dims
        float pl0 = 0.f, pl1 = 0.f;
        #pragma unroll
        for (int k = 0; k < 8; ++k){
          pl0 += s_kloc[k*128 + tid]      * s_q8[k];
          pl1 += s_kloc[k*128 + tid + 64] * s_q8[k];
        }
        gst64(&XP[((size_t)(dslot*64 + tid))*64 + b],
              ((u64)ph<<32) | (u32)f2bf(pl0) | ((u32)f2bf(pl1)<<16));
      }
      if (tid == 64){
        float p0 = 0.f, p1 = 0.f;
        #pragma unroll
        for (int i = 0; i < 8; ++i){ p0 += s_red[i*2]; p1 += s_red[i*2+1]; }
        gst64(&XE[eslot*64 + b], ((u64)ph<<32) | (u32)f2bf(p0) | ((u32)f2bf(p1)<<16));
      }
      if (tid < 512) s_curv[tid] = s_nc[tid];
      SHIFT_JOBS();
      aeV=1; aeSlot=eslot; aeSel=0; aeOwn=ecnt&63; aeTag=ph; ecnt++;
      dAV=1; dASlot=dslot; dAo1=(2*dcnt)&63; dAo2=(2*dcnt+1)&63; dAcur=cur; dAarg=arg; dATag=ph;
      dcnt++;
      ph += 1;
    }
  }

  // ---------------- drain: V1 (final SE partials + last stage-B), V2 (collect) ----------------
  {
    int eslot = ecnt & 3;
    u32 gtag = ph-1; int gpar = gtag & 1;
    if (tid < 512){ u64 v = pollt(&Xng[(gpar*512+tid)*2+1], gtag); s_g[tid] = u2f((u32)v); }
    __syncthreads();
    RUN_JOBS();                               // jobs due this phase
    if (have_se && wv < 8){
      float4 xg_a = *(float4*)&s_g[lane*8], xg_b = *(float4*)&s_g[lane*8+4];
      float4 xc_a = *(float4*)&s_curv[lane*8], xc_b = *(float4*)&s_curv[lane*8+4];
      const u32* Re = (const u32*)s_we1 + wv*512;
      float pe = dot8p(*(const uint4*)&Re[lane*4], xg_a,xg_b) + dot8p(*(const uint4*)&Re[256+lane*4], xc_a,xc_b);
      float hv = fmaxf(wred(pe) + be1w, 0.f);
      if (lane == 0){ s_red[wv*2] = hv*we2_0; s_red[wv*2+1] = hv*we2_1; }
    }
    __syncthreads();
    if (have_se && tid == 0){
      float p0 = 0.f, p1 = 0.f;
      #pragma unroll
      for (int i = 0; i < 8; ++i){ p0 += s_red[i*2]; p1 += s_red[i*2+1]; }
      gst64(&XE[eslot*64 + b], ((u64)ph<<32) | (u32)f2bf(p0) | ((u32)f2bf(p1)<<16));
    }
    SHIFT_JOBS();
    RUN_JOBS();                               // stage-B of the last CHOOSE_DEST
    if (wv == 8){
      if (have_se && b == 0){
        u64 v = pollt(&XE[eslot*64 + lane], ph);
        float p0 = wredsh(bf2f((u16)(v & 0xffff)));
        float p1 = wredsh(bf2f((u16)((v>>16) & 0xffff)));
        if (lane == 0){
          float l0 = p0 + be2_0, l1 = p1 + be2_1;
          float m = fmaxf(l0, l1);
          nllw += m + logf(__expf(l0-m) + __expf(l1-m)) - l1;   // STOP_EDGE selects idx 1
        }
      }
      if (lane == 0) gst64(&XN[b], (0xFFFFull<<32) | f2u(nllw));
      if (b == 0){
        u64 v = pollt(&XN[lane], 0xFFFFu);
        float tot = wredsh(u2f((u32)v));
        if (lane == 0) out[0] = tot;
      }
    }
  }
}

extern "C" void kernel_launch(void* const* d_in, const int* in_sizes, int n_in,
                              void* d_out, int out_size, void* d_ws, size_t ws_size,
                              hipStream_t stream) {
  (void)in_sizes; (void)n_in; (void)out_size; (void)ws_size;
  // zero all tag-atom regions (19520 u64) — exact-match tags then poison/replay-safe
  hipMemsetAsync(d_ws, 0, 156160, stream);
  hipFuncSetAttribute((const void*)dgmg_kernel,
                      hipFuncAttributeMaxDynamicSharedMemorySize, SMEM_BYTES);
  dgmg_kernel<<<NBLK, NTHR, SMEM_BYTES, stream>>>(
      (const int*)d_in[0], (const int*)d_in[1],
      (const float*)d_in[2], (const float*)d_in[3], (const float*)d_in[4],
      (const float*)d_in[5], (const float*)d_in[6],
      (const float*)d_in[7], (const float*)d_in[8],
      (const float*)d_in[9], (const float*)d_in[10],
      (const float*)d_in[11],                      /* w_k ; b_k unused (cancels) */
      (const float*)d_in[13], (const float*)d_in[14],
      (const float*)d_in[15], (const float*)d_in[16],
      (const float*)d_in[17], (const float*)d_in[18],
      (const float*)d_in[19], (const float*)d_in[20],
      (const float*)d_in[21],
      (float*)d_out, (unsigned char*)d_ws);
}